// Round 12
// baseline (45.089 us; speedup 1.0000x reference)
//
#include <hip/hip_runtime.h>
#include <hip/hip_bf16.h>

// Problem constants (from reference)
#define Hd   768
#define Bsz  4
#define Ent  42
#define Mm   16
#define NEGV (-1e9f)

#define GM 2688          // B*E*M rows
#define GN 1536          // concat(head, tail) outputs
#define GK 768
#define NT2 (GK / 64)    // 12 K-steps of 64

typedef short bf16x8 __attribute__((ext_vector_type(8)));
typedef float f32x4  __attribute__((ext_vector_type(4)));
typedef unsigned short u16x8 __attribute__((ext_vector_type(8)));
typedef unsigned short u16x4 __attribute__((ext_vector_type(4)));

static __device__ __forceinline__ unsigned short f2bf(float x) {
    unsigned int u = __float_as_uint(x);
    u += 0x7fffu + ((u >> 16) & 1u);          // RNE
    return (unsigned short)(u >> 16);
}
static __device__ __forceinline__ float bf2f(unsigned short v) {
    return __uint_as_float(((unsigned int)v) << 16);
}

// ---------------------------------------------------------------------------
// Kernel 0: fp32 -> bf16 conversion (round-7 proven).
// ---------------------------------------------------------------------------
__global__ __launch_bounds__(256)
void to_bf16(const float* __restrict__ me, const float* __restrict__ wh,
             const float* __restrict__ wt, unsigned short* __restrict__ dst)
{
    const int t = blockIdx.x * 256 + threadIdx.x;
    const size_t e = (size_t)t * 8;
    const size_t row = e / Hd;                         // 8 | 768 so no straddle
    const float* src;
    size_t off;
    if (row < 2688)      { src = me; off = e; }
    else if (row < 3456) { src = wh; off = e - (size_t)2688 * Hd; }
    else                 { src = wt; off = e - (size_t)3456 * Hd; }
    float4 v0 = *reinterpret_cast<const float4*>(src + off);
    float4 v1 = *reinterpret_cast<const float4*>(src + off + 4);
    u16x8 o;
    o[0] = f2bf(v0.x); o[1] = f2bf(v0.y); o[2] = f2bf(v0.z); o[3] = f2bf(v0.w);
    o[4] = f2bf(v1.x); o[5] = f2bf(v1.y); o[6] = f2bf(v1.z); o[7] = f2bf(v1.w);
    *reinterpret_cast<u16x8*>(dst + e) = o;
}

// ---------------------------------------------------------------------------
// Kernel 1: bf16 MFMA GEMM + ReLU, BK=64 + T2 both-sides swizzle (round-10
// proven) + T1 XCD-aware block swizzle.  504 blocks % 8 XCDs == 0 ->
// bijective chunked remap; bx-major decode so each XCD keeps ~2 B-panels
// (0.75 MB) L2-resident instead of streaming all 12 (4.5 MB) through L3.
// Tile->block reassignment only: output bits identical.
// ---------------------------------------------------------------------------
__global__ __launch_bounds__(256)
void gemm_mfma(const unsigned short* __restrict__ Ab,
               const unsigned short* __restrict__ Wb,
               unsigned short* __restrict__ f_head,
               unsigned short* __restrict__ f_tail)
{
    __shared__ unsigned short As[2][64 * 64];    //  8 KB per buf
    __shared__ unsigned short Bs[2][128 * 64];   // 16 KB per buf

    const int tid  = threadIdx.x;
    const int wave = tid >> 6;
    const int lane = tid & 63;

    // T1: XCD swizzle. 504 = 8 * 63 exactly; bx-major for B-panel residency.
    const int swz = (blockIdx.x & 7) * 63 + (blockIdx.x >> 3);
    const int n0 = (swz / 42) * 128;     // bx in [0,12)
    const int m0 = (swz % 42) * 64;      // by in [0,42)

    const int sr8   = lane >> 3;                       // 0..7 row in stripe
    const int scolE = ((lane & 7) ^ sr8) * 8;          // swizzled src col (elems)
    const unsigned short* AgaBase = Ab + (size_t)(m0 + wave * 16 + sr8) * GK + scolE;
    const unsigned short* BgaBase = Wb + (size_t)(n0 + wave * 32 + sr8) * GK + scolE;

#define STAGE(buf, k0) do { \
    __builtin_amdgcn_global_load_lds((const __attribute__((address_space(1))) void*)(AgaBase + (k0)), \
        (__attribute__((address_space(3))) void*)(As[buf] + (wave * 16) * 64), 16, 0, 0); \
    __builtin_amdgcn_global_load_lds((const __attribute__((address_space(1))) void*)(AgaBase + 8 * GK + (k0)), \
        (__attribute__((address_space(3))) void*)(As[buf] + (wave * 16 + 8) * 64), 16, 0, 0); \
    __builtin_amdgcn_global_load_lds((const __attribute__((address_space(1))) void*)(BgaBase + (k0)), \
        (__attribute__((address_space(3))) void*)(Bs[buf] + (wave * 32) * 64), 16, 0, 0); \
    __builtin_amdgcn_global_load_lds((const __attribute__((address_space(1))) void*)(BgaBase + 8 * GK + (k0)), \
        (__attribute__((address_space(3))) void*)(Bs[buf] + (wave * 32 + 8) * 64), 16, 0, 0); \
    __builtin_amdgcn_global_load_lds((const __attribute__((address_space(1))) void*)(BgaBase + 16 * GK + (k0)), \
        (__attribute__((address_space(3))) void*)(Bs[buf] + (wave * 32 + 16) * 64), 16, 0, 0); \
    __builtin_amdgcn_global_load_lds((const __attribute__((address_space(1))) void*)(BgaBase + 24 * GK + (k0)), \
        (__attribute__((address_space(3))) void*)(Bs[buf] + (wave * 32 + 24) * 64), 16, 0, 0); \
} while (0)

    const int frow = lane & 15;
    const int kg   = lane >> 4;
    const int f7x  = (frow & 7) << 4;                  // byte XOR key (row-det.)
    const int rdE0 = ((kg * 16)      ^ f7x) >> 1;      // elems, k-half 0
    const int rdE1 = ((kg * 16 + 64) ^ f7x) >> 1;      // elems, k-half 1

    f32x4 acc[4][2];
    {
        f32x4 z = {0.f, 0.f, 0.f, 0.f};
        #pragma unroll
        for (int mi = 0; mi < 4; ++mi) { acc[mi][0] = z; acc[mi][1] = z; }
    }

    STAGE(0, 0);
    int cur = 0;
    #pragma unroll 1
    for (int t = 0; t < NT2; ++t) {
        __syncthreads();                 // drains vmcnt: buf[cur] ready
        if (t < NT2 - 1) STAGE(cur ^ 1, (t + 1) * 64);
        const unsigned short* a_ = As[cur] + frow * 64;
        const unsigned short* b_ = Bs[cur] + (wave * 32 + frow) * 64;
        bf16x8 a[4][2], b[2][2];
        #pragma unroll
        for (int mi = 0; mi < 4; ++mi) {
            a[mi][0] = *reinterpret_cast<const bf16x8*>(a_ + mi * 16 * 64 + rdE0);
            a[mi][1] = *reinterpret_cast<const bf16x8*>(a_ + mi * 16 * 64 + rdE1);
        }
        #pragma unroll
        for (int ni = 0; ni < 2; ++ni) {
            b[ni][0] = *reinterpret_cast<const bf16x8*>(b_ + ni * 16 * 64 + rdE0);
            b[ni][1] = *reinterpret_cast<const bf16x8*>(b_ + ni * 16 * 64 + rdE1);
        }
        #pragma unroll
        for (int kk = 0; kk < 2; ++kk)           // ascending k: bit-identical
            #pragma unroll
            for (int mi = 0; mi < 4; ++mi) {
                acc[mi][0] = __builtin_amdgcn_mfma_f32_16x16x32_bf16(a[mi][kk], b[0][kk], acc[mi][0], 0, 0, 0);
                acc[mi][1] = __builtin_amdgcn_mfma_f32_16x16x32_bf16(a[mi][kk], b[1][kk], acc[mi][1], 0, 0, 0);
            }
        cur ^= 1;
    }
#undef STAGE

    // C/D layout (m89-verified): col = frow, row = kg*4 + reg.
    const bool isHead = (n0 < Hd);
    unsigned short* outp = isHead ? f_head : f_tail;
    const int nbase = (isHead ? n0 : (n0 - Hd)) + wave * 32 + frow;
    const int rbase = m0 + kg * 4;
    #pragma unroll
    for (int mi = 0; mi < 4; ++mi)
        #pragma unroll
        for (int ni = 0; ni < 2; ++ni)
            #pragma unroll
            for (int j = 0; j < 4; ++j) {
                float v = fmaxf(acc[mi][ni][j], 0.f);
                outp[(size_t)(rbase + mi * 16 + j) * Hd + nbase + ni * 16] = f2bf(v);
            }
}

// ---------------------------------------------------------------------------
// Kernel 2: per-row dots (round-7 proven).
// ---------------------------------------------------------------------------
__global__ __launch_bounds__(256)
void row_dots(const unsigned short* __restrict__ f_head,
              const unsigned short* __restrict__ f_tail,
              const float* __restrict__ w_c, const float* __restrict__ w_q,
              const float* __restrict__ w_cq,
              float* __restrict__ ch, float* __restrict__ qt, float* __restrict__ cqt)
{
    const int wave = threadIdx.x >> 6;
    const int lane = threadIdx.x & 63;
    const int r = blockIdx.x * 4 + wave;
    const unsigned short* fh = f_head + (size_t)r * Hd;
    const unsigned short* ft = f_tail + (size_t)r * Hd;
    float pc = 0.f, pq = 0.f, pcq = 0.f;
    #pragma unroll
    for (int j = 0; j < Hd / 64; ++j) {
        const int c = j * 64 + lane;
        float vh = bf2f(fh[c]), vt = bf2f(ft[c]);
        pc += vh * w_c[c]; pq += vt * w_q[c]; pcq += vt * w_cq[c];
    }
    #pragma unroll
    for (int s = 32; s >= 1; s >>= 1) {
        pc  += __shfl_down(pc, s);
        pq  += __shfl_down(pq, s);
        pcq += __shfl_down(pcq, s);
    }
    if (lane == 0) { ch[r] = pc; qt[r] = pq; cqt[r] = pcq; }
}

// ---------------------------------------------------------------------------
// Weighted pooling helper: one pass over rows, 3 chunks/row, 4 rows/step
// (12 loads in flight).  Per-accumulator fma order stays ascending-ii ->
// bit-identical to the 2-row and 1-row versions.
// ---------------------------------------------------------------------------
static __device__ __forceinline__ void pool_rows(
    const unsigned short* __restrict__ fp, const float* wgt, int cnt,
    int lane, float* __restrict__ dst)
{
    float a[12];
    #pragma unroll
    for (int j = 0; j < 12; ++j) a[j] = 0.f;
    int ii = 0;
    for (; ii + 4 <= cnt; ii += 4) {
        u16x4 r0[3], r1[3], r2[3], r3[3];
        #pragma unroll
        for (int c = 0; c < 3; ++c) {
            const size_t co = c * 256 + lane * 4;
            r0[c] = *reinterpret_cast<const u16x4*>(fp + (size_t)ii * Hd + co);
            r1[c] = *reinterpret_cast<const u16x4*>(fp + (size_t)(ii + 1) * Hd + co);
            r2[c] = *reinterpret_cast<const u16x4*>(fp + (size_t)(ii + 2) * Hd + co);
            r3[c] = *reinterpret_cast<const u16x4*>(fp + (size_t)(ii + 3) * Hd + co);
        }
        const float w0 = wgt[ii], w1 = wgt[ii + 1], w2 = wgt[ii + 2], w3 = wgt[ii + 3];
        #pragma unroll
        for (int c = 0; c < 3; ++c)
            #pragma unroll
            for (int k = 0; k < 4; ++k) {
                a[c * 4 + k] += w0 * bf2f(r0[c][k]);   // ascending ii:
                a[c * 4 + k] += w1 * bf2f(r1[c][k]);   // bit-identical order
                a[c * 4 + k] += w2 * bf2f(r2[c][k]);
                a[c * 4 + k] += w3 * bf2f(r3[c][k]);
            }
    }
    for (; ii + 2 <= cnt; ii += 2) {
        u16x4 r0[3], r1[3];
        #pragma unroll
        for (int c = 0; c < 3; ++c) {
            const size_t co = c * 256 + lane * 4;
            r0[c] = *reinterpret_cast<const u16x4*>(fp + (size_t)ii * Hd + co);
            r1[c] = *reinterpret_cast<const u16x4*>(fp + (size_t)(ii + 1) * Hd + co);
        }
        const float w0 = wgt[ii], w1 = wgt[ii + 1];
        #pragma unroll
        for (int c = 0; c < 3; ++c)
            #pragma unroll
            for (int k = 0; k < 4; ++k) {
                a[c * 4 + k] += w0 * bf2f(r0[c][k]);
                a[c * 4 + k] += w1 * bf2f(r1[c][k]);
            }
    }
    if (ii < cnt) {
        u16x4 r0[3];
        #pragma unroll
        for (int c = 0; c < 3; ++c)
            r0[c] = *reinterpret_cast<const u16x4*>(fp + (size_t)ii * Hd + c * 256 + lane * 4);
        const float w0 = wgt[ii];
        #pragma unroll
        for (int c = 0; c < 3; ++c)
            #pragma unroll
            for (int k = 0; k < 4; ++k)
                a[c * 4 + k] += w0 * bf2f(r0[c][k]);
    }
    #pragma unroll
    for (int c = 0; c < 3; ++c) {
        float4 o = {a[c * 4], a[c * 4 + 1], a[c * 4 + 2], a[c * 4 + 3]};
        *reinterpret_cast<float4*>(dst + c * 256 + lane * 4) = o;
    }
}

// ---------------------------------------------------------------------------
// Kernel 3: ONE WAVE PER PAIR attention (round-11 structure; pooling deepened
// to 4 rows/step via pool_rows).
// ---------------------------------------------------------------------------
__global__ __launch_bounds__(256)
void pair_attn(const unsigned short* __restrict__ f_head,
               const unsigned short* __restrict__ f_tail,
               const float* __restrict__ ch, const float* __restrict__ qt,
               const float* __restrict__ cqt,
               const float* __restrict__ entity_embed,
               const int* __restrict__ mention_num,
               const int* __restrict__ b_ind, const int* __restrict__ h_ind,
               const int* __restrict__ t_ind,
               float* __restrict__ out, int N)
{
    const int tid  = threadIdx.x;
    const int wave = tid >> 6;
    const int lane = tid & 63;

    __shared__ float hwS[4][16];
    __shared__ float twS[4][16];

    int n = blockIdx.x * 4 + wave;
    if (n >= N) n = N - 1;      // duplicate pair: identical writes, deterministic

    const int b = b_ind[n], h = h_ind[n], t = t_ind[n];
    const int eh = b * Ent + h, et = b * Ent + t;
    const int rh = eh * Mm, rt = et * Mm;
    const int hn = mention_num[eh], tn = mention_num[et];

    const int i  = lane >> 2;       // score row 0..15
    const int jg = lane & 3;        // col group: cols jg*4 .. jg*4+3

    const float chi = ch[rh + i];
    const float cqi = cqt[rt + i];
    const float4 q4 = *reinterpret_cast<const float4*>(qt + rt + jg * 4);
    const u16x4 f4  = *reinterpret_cast<const u16x4*>(
                          f_head + (size_t)(rh + i) * Hd + jg * 4);
    float v[4];
    #pragma unroll
    for (int k = 0; k < 4; ++k) {
        const int j = jg * 4 + k;
        const float qv = (k == 0) ? q4.x : (k == 1) ? q4.y : (k == 2) ? q4.z : q4.w;
        v[k] = (i < hn && j < tn) ? (chi + qv + cqi * bf2f(f4[k])) : NEGV;
    }

    float rm = fmaxf(fmaxf(v[0], v[1]), fmaxf(v[2], v[3]));
    rm = fmaxf(rm, __shfl_xor(rm, 1));
    rm = fmaxf(rm, __shfl_xor(rm, 2));

    float cm[4];
    #pragma unroll
    for (int k = 0; k < 4; ++k) {
        cm[k] = v[k];
        cm[k] = fmaxf(cm[k], __shfl_xor(cm[k], 4));
        cm[k] = fmaxf(cm[k], __shfl_xor(cm[k], 8));
        cm[k] = fmaxf(cm[k], __shfl_xor(cm[k], 16));
        cm[k] = fmaxf(cm[k], __shfl_xor(cm[k], 32));
    }

    float gm = rm;
    gm = fmaxf(gm, __shfl_xor(gm, 4));
    gm = fmaxf(gm, __shfl_xor(gm, 8));
    gm = fmaxf(gm, __shfl_xor(gm, 16));
    gm = fmaxf(gm, __shfl_xor(gm, 32));
    const float eh_ = expf(rm - gm);
    float S = eh_;
    S += __shfl_xor(S, 4);
    S += __shfl_xor(S, 8);
    S += __shfl_xor(S, 16);
    S += __shfl_xor(S, 32);
    const float hwv = eh_ / S;

    float gmt = fmaxf(fmaxf(cm[0], cm[1]), fmaxf(cm[2], cm[3]));
    gmt = fmaxf(gmt, __shfl_xor(gmt, 1));
    gmt = fmaxf(gmt, __shfl_xor(gmt, 2));
    float et_[4];
    float St = 0.f;
    #pragma unroll
    for (int k = 0; k < 4; ++k) { et_[k] = expf(cm[k] - gmt); St += et_[k]; }
    St += __shfl_xor(St, 1);
    St += __shfl_xor(St, 2);

    if (jg == 0) hwS[wave][i] = hwv;
    if (lane < 4) {
        #pragma unroll
        for (int k = 0; k < 4; ++k) twS[wave][lane * 4 + k] = et_[k] / St;
    }
    __syncthreads();

    const size_t oh = (size_t)n * (2 * Hd);
    const size_t ot = (size_t)(N + n) * (2 * Hd);

    pool_rows(f_head + (size_t)rh * Hd, hwS[wave], hn, lane, out + oh + Hd);
    pool_rows(f_tail + (size_t)rt * Hd, twS[wave], tn, lane, out + ot + Hd);

    // ---- entity embed copy: 2 x 192 float4, lane covers 3 each ----
    const float4* ehp = reinterpret_cast<const float4*>(entity_embed + (size_t)eh * Hd);
    const float4* etp = reinterpret_cast<const float4*>(entity_embed + (size_t)et * Hd);
    #pragma unroll
    for (int c = 0; c < 3; ++c) {
        const int g = c * 64 + lane;
        reinterpret_cast<float4*>(out + oh)[g] = ehp[g];
        reinterpret_cast<float4*>(out + ot)[g] = etp[g];
    }
}

// ---------------------------------------------------------------------------
extern "C" void kernel_launch(void* const* d_in, const int* in_sizes, int n_in,
                              void* d_out, int out_size, void* d_ws, size_t ws_size,
                              hipStream_t stream)
{
    const float* entity_embed  = (const float*)d_in[0];
    const float* mention_embed = (const float*)d_in[1];
    // d_in[2] sent_embed, d_in[3] entity_info: unused by reference
    const int*   mention_num   = (const int*)d_in[4];
    const int*   b_ind         = (const int*)d_in[5];
    const int*   h_ind         = (const int*)d_in[6];
    const int*   t_ind         = (const int*)d_in[7];
    const float* W_head        = (const float*)d_in[8];
    const float* W_tail        = (const float*)d_in[9];
    const float* w_c           = (const float*)d_in[10];
    const float* w_q           = (const float*)d_in[11];
    const float* w_cq          = (const float*)d_in[12];
    float* out = (float*)d_out;

    const int N = in_sizes[5];            // 4096

    // workspace layout (bf16 activations): total ~14.8 MiB
    unsigned short* Ab     = (unsigned short*)d_ws;          // [2688*768]
    unsigned short* Wb     = Ab + (size_t)GM * GK;           // [1536*768] (head||tail)
    unsigned short* f_head = Wb + (size_t)GN * GK;           // [2688*768]
    unsigned short* f_tail = f_head + (size_t)GM * Hd;       // [2688*768]
    float* ch  = (float*)(f_tail + (size_t)GM * Hd);         // [2688]
    float* qt  = ch + GM;                                    // [2688]
    float* cqt = qt + GM;                                    // [2688]

    // 0) convert inputs to bf16
    to_bf16<<<(GM + GN) * GK / (8 * 256), 256, 0, stream>>>(
        mention_embed, W_head, W_tail, Ab);

    // 1) GEMM + ReLU (BK=64, swizzled LDS, XCD-swizzled 1-D grid)
    gemm_mfma<<<504, 256, 0, stream>>>(Ab, Wb, f_head, f_tail);

    // 2) per-row dots
    row_dots<<<GM / 4, 256, 0, stream>>>(f_head, f_tail, w_c, w_q, w_cq, ch, qt, cqt);

    // 3) per-pair attention + output (wave per pair, 4-row MLP pooling)
    pair_attn<<<(N + 3) / 4, 256, 0, stream>>>(f_head, f_tail, ch, qt, cqt,
                                               entity_embed, mention_num,
                                               b_ind, h_ind, t_ind, out, N);
}

// Round 13
// 44.226 us; speedup vs baseline: 1.0195x; 1.0195x over previous
//
#include <hip/hip_runtime.h>
#include <hip/hip_bf16.h>

// Problem constants (from reference)
#define Hd   768
#define Bsz  4
#define Ent  42
#define Mm   16
#define NEGV (-1e9f)

#define GM 2688          // B*E*M rows
#define GN 1536          // concat(head, tail) outputs
#define GK 768
#define NT2 (GK / 64)    // 12 K-steps of 64

typedef short bf16x8 __attribute__((ext_vector_type(8)));
typedef float f32x4  __attribute__((ext_vector_type(4)));
typedef unsigned short u16x8 __attribute__((ext_vector_type(8)));
typedef unsigned short u16x4 __attribute__((ext_vector_type(4)));

static __device__ __forceinline__ unsigned short f2bf(float x) {
    unsigned int u = __float_as_uint(x);
    u += 0x7fffu + ((u >> 16) & 1u);          // RNE
    return (unsigned short)(u >> 16);
}
static __device__ __forceinline__ float bf2f(unsigned short v) {
    return __uint_as_float(((unsigned int)v) << 16);
}

// ---------------------------------------------------------------------------
// Kernel 0: fp32 -> bf16 conversion (round-7 proven).
// ---------------------------------------------------------------------------
__global__ __launch_bounds__(256)
void to_bf16(const float* __restrict__ me, const float* __restrict__ wh,
             const float* __restrict__ wt, unsigned short* __restrict__ dst)
{
    const int t = blockIdx.x * 256 + threadIdx.x;
    const size_t e = (size_t)t * 8;
    const size_t row = e / Hd;                         // 8 | 768 so no straddle
    const float* src;
    size_t off;
    if (row < 2688)      { src = me; off = e; }
    else if (row < 3456) { src = wh; off = e - (size_t)2688 * Hd; }
    else                 { src = wt; off = e - (size_t)3456 * Hd; }
    float4 v0 = *reinterpret_cast<const float4*>(src + off);
    float4 v1 = *reinterpret_cast<const float4*>(src + off + 4);
    u16x8 o;
    o[0] = f2bf(v0.x); o[1] = f2bf(v0.y); o[2] = f2bf(v0.z); o[3] = f2bf(v0.w);
    o[4] = f2bf(v1.x); o[5] = f2bf(v1.y); o[6] = f2bf(v1.z); o[7] = f2bf(v1.w);
    *reinterpret_cast<u16x8*>(dst + e) = o;
}

// ---------------------------------------------------------------------------
// Kernel 1: bf16 MFMA GEMM + ReLU, BK=64 + T2 both-sides swizzle
// (round-10 proven, byte-identical -- round-12's T1 swizzle reverted:
// B operand is 2.25 MB, already L2-resident per XCD, so T1's regime
// prerequisite is absent and it measured neutral).
// ---------------------------------------------------------------------------
__global__ __launch_bounds__(256)
void gemm_mfma(const unsigned short* __restrict__ Ab,
               const unsigned short* __restrict__ Wb,
               unsigned short* __restrict__ f_head,
               unsigned short* __restrict__ f_tail)
{
    __shared__ unsigned short As[2][64 * 64];    //  8 KB per buf
    __shared__ unsigned short Bs[2][128 * 64];   // 16 KB per buf

    const int tid  = threadIdx.x;
    const int wave = tid >> 6;
    const int lane = tid & 63;
    const int n0 = blockIdx.x * 128;
    const int m0 = blockIdx.y * 64;

    const int sr8   = lane >> 3;                       // 0..7 row in stripe
    const int scolE = ((lane & 7) ^ sr8) * 8;          // swizzled src col (elems)
    const unsigned short* AgaBase = Ab + (size_t)(m0 + wave * 16 + sr8) * GK + scolE;
    const unsigned short* BgaBase = Wb + (size_t)(n0 + wave * 32 + sr8) * GK + scolE;

#define STAGE(buf, k0) do { \
    __builtin_amdgcn_global_load_lds((const __attribute__((address_space(1))) void*)(AgaBase + (k0)), \
        (__attribute__((address_space(3))) void*)(As[buf] + (wave * 16) * 64), 16, 0, 0); \
    __builtin_amdgcn_global_load_lds((const __attribute__((address_space(1))) void*)(AgaBase + 8 * GK + (k0)), \
        (__attribute__((address_space(3))) void*)(As[buf] + (wave * 16 + 8) * 64), 16, 0, 0); \
    __builtin_amdgcn_global_load_lds((const __attribute__((address_space(1))) void*)(BgaBase + (k0)), \
        (__attribute__((address_space(3))) void*)(Bs[buf] + (wave * 32) * 64), 16, 0, 0); \
    __builtin_amdgcn_global_load_lds((const __attribute__((address_space(1))) void*)(BgaBase + 8 * GK + (k0)), \
        (__attribute__((address_space(3))) void*)(Bs[buf] + (wave * 32 + 8) * 64), 16, 0, 0); \
    __builtin_amdgcn_global_load_lds((const __attribute__((address_space(1))) void*)(BgaBase + 16 * GK + (k0)), \
        (__attribute__((address_space(3))) void*)(Bs[buf] + (wave * 32 + 16) * 64), 16, 0, 0); \
    __builtin_amdgcn_global_load_lds((const __attribute__((address_space(1))) void*)(BgaBase + 24 * GK + (k0)), \
        (__attribute__((address_space(3))) void*)(Bs[buf] + (wave * 32 + 24) * 64), 16, 0, 0); \
} while (0)

    const int frow = lane & 15;
    const int kg   = lane >> 4;
    const int f7x  = (frow & 7) << 4;                  // byte XOR key (row-det.)
    const int rdE0 = ((kg * 16)      ^ f7x) >> 1;      // elems, k-half 0
    const int rdE1 = ((kg * 16 + 64) ^ f7x) >> 1;      // elems, k-half 1

    f32x4 acc[4][2];
    {
        f32x4 z = {0.f, 0.f, 0.f, 0.f};
        #pragma unroll
        for (int mi = 0; mi < 4; ++mi) { acc[mi][0] = z; acc[mi][1] = z; }
    }

    STAGE(0, 0);
    int cur = 0;
    #pragma unroll 1
    for (int t = 0; t < NT2; ++t) {
        __syncthreads();                 // drains vmcnt: buf[cur] ready
        if (t < NT2 - 1) STAGE(cur ^ 1, (t + 1) * 64);
        const unsigned short* a_ = As[cur] + frow * 64;
        const unsigned short* b_ = Bs[cur] + (wave * 32 + frow) * 64;
        bf16x8 a[4][2], b[2][2];
        #pragma unroll
        for (int mi = 0; mi < 4; ++mi) {
            a[mi][0] = *reinterpret_cast<const bf16x8*>(a_ + mi * 16 * 64 + rdE0);
            a[mi][1] = *reinterpret_cast<const bf16x8*>(a_ + mi * 16 * 64 + rdE1);
        }
        #pragma unroll
        for (int ni = 0; ni < 2; ++ni) {
            b[ni][0] = *reinterpret_cast<const bf16x8*>(b_ + ni * 16 * 64 + rdE0);
            b[ni][1] = *reinterpret_cast<const bf16x8*>(b_ + ni * 16 * 64 + rdE1);
        }
        #pragma unroll
        for (int kk = 0; kk < 2; ++kk)           // ascending k: bit-identical
            #pragma unroll
            for (int mi = 0; mi < 4; ++mi) {
                acc[mi][0] = __builtin_amdgcn_mfma_f32_16x16x32_bf16(a[mi][kk], b[0][kk], acc[mi][0], 0, 0, 0);
                acc[mi][1] = __builtin_amdgcn_mfma_f32_16x16x32_bf16(a[mi][kk], b[1][kk], acc[mi][1], 0, 0, 0);
            }
        cur ^= 1;
    }
#undef STAGE

    // C/D layout (m89-verified): col = frow, row = kg*4 + reg.
    const bool isHead = (n0 < Hd);
    unsigned short* outp = isHead ? f_head : f_tail;
    const int nbase = (isHead ? n0 : (n0 - Hd)) + wave * 32 + frow;
    const int rbase = m0 + kg * 4;
    #pragma unroll
    for (int mi = 0; mi < 4; ++mi)
        #pragma unroll
        for (int ni = 0; ni < 2; ++ni)
            #pragma unroll
            for (int j = 0; j < 4; ++j) {
                float v = fmaxf(acc[mi][ni][j], 0.f);
                outp[(size_t)(rbase + mi * 16 + j) * Hd + nbase + ni * 16] = f2bf(v);
            }
}

// ---------------------------------------------------------------------------
// Kernel 2: per-row dots (round-7 proven).
// ---------------------------------------------------------------------------
__global__ __launch_bounds__(256)
void row_dots(const unsigned short* __restrict__ f_head,
              const unsigned short* __restrict__ f_tail,
              const float* __restrict__ w_c, const float* __restrict__ w_q,
              const float* __restrict__ w_cq,
              float* __restrict__ ch, float* __restrict__ qt, float* __restrict__ cqt)
{
    const int wave = threadIdx.x >> 6;
    const int lane = threadIdx.x & 63;
    const int r = blockIdx.x * 4 + wave;
    const unsigned short* fh = f_head + (size_t)r * Hd;
    const unsigned short* ft = f_tail + (size_t)r * Hd;
    float pc = 0.f, pq = 0.f, pcq = 0.f;
    #pragma unroll
    for (int j = 0; j < Hd / 64; ++j) {
        const int c = j * 64 + lane;
        float vh = bf2f(fh[c]), vt = bf2f(ft[c]);
        pc += vh * w_c[c]; pq += vt * w_q[c]; pcq += vt * w_cq[c];
    }
    #pragma unroll
    for (int s = 32; s >= 1; s >>= 1) {
        pc  += __shfl_down(pc, s);
        pq  += __shfl_down(pq, s);
        pcq += __shfl_down(pcq, s);
    }
    if (lane == 0) { ch[r] = pc; qt[r] = pq; cqt[r] = pcq; }
}

// ---------------------------------------------------------------------------
// Kernel 3: ONE WAVE PER PAIR attention (round-11 proven, byte-identical).
// Pooling: single pass over rows per half, 3 independent chunk-loads per row,
// 2 rows per step (6 loads in flight).  Ascending-ii fma order: bit-exact.
// ---------------------------------------------------------------------------
__global__ __launch_bounds__(256)
void pair_attn(const unsigned short* __restrict__ f_head,
               const unsigned short* __restrict__ f_tail,
               const float* __restrict__ ch, const float* __restrict__ qt,
               const float* __restrict__ cqt,
               const float* __restrict__ entity_embed,
               const int* __restrict__ mention_num,
               const int* __restrict__ b_ind, const int* __restrict__ h_ind,
               const int* __restrict__ t_ind,
               float* __restrict__ out, int N)
{
    const int tid  = threadIdx.x;
    const int wave = tid >> 6;
    const int lane = tid & 63;

    __shared__ float hwS[4][16];
    __shared__ float twS[4][16];

    int n = blockIdx.x * 4 + wave;
    if (n >= N) n = N - 1;      // duplicate pair: identical writes, deterministic

    const int b = b_ind[n], h = h_ind[n], t = t_ind[n];
    const int eh = b * Ent + h, et = b * Ent + t;
    const int rh = eh * Mm, rt = et * Mm;
    const int hn = mention_num[eh], tn = mention_num[et];

    const int i  = lane >> 2;       // score row 0..15
    const int jg = lane & 3;        // col group: cols jg*4 .. jg*4+3

    const float chi = ch[rh + i];
    const float cqi = cqt[rt + i];
    const float4 q4 = *reinterpret_cast<const float4*>(qt + rt + jg * 4);
    const u16x4 f4  = *reinterpret_cast<const u16x4*>(
                          f_head + (size_t)(rh + i) * Hd + jg * 4);
    float v[4];
    #pragma unroll
    for (int k = 0; k < 4; ++k) {
        const int j = jg * 4 + k;
        const float qv = (k == 0) ? q4.x : (k == 1) ? q4.y : (k == 2) ? q4.z : q4.w;
        v[k] = (i < hn && j < tn) ? (chi + qv + cqi * bf2f(f4[k])) : NEGV;
    }

    float rm = fmaxf(fmaxf(v[0], v[1]), fmaxf(v[2], v[3]));
    rm = fmaxf(rm, __shfl_xor(rm, 1));
    rm = fmaxf(rm, __shfl_xor(rm, 2));

    float cm[4];
    #pragma unroll
    for (int k = 0; k < 4; ++k) {
        cm[k] = v[k];
        cm[k] = fmaxf(cm[k], __shfl_xor(cm[k], 4));
        cm[k] = fmaxf(cm[k], __shfl_xor(cm[k], 8));
        cm[k] = fmaxf(cm[k], __shfl_xor(cm[k], 16));
        cm[k] = fmaxf(cm[k], __shfl_xor(cm[k], 32));
    }

    float gm = rm;
    gm = fmaxf(gm, __shfl_xor(gm, 4));
    gm = fmaxf(gm, __shfl_xor(gm, 8));
    gm = fmaxf(gm, __shfl_xor(gm, 16));
    gm = fmaxf(gm, __shfl_xor(gm, 32));
    const float eh_ = expf(rm - gm);
    float S = eh_;
    S += __shfl_xor(S, 4);
    S += __shfl_xor(S, 8);
    S += __shfl_xor(S, 16);
    S += __shfl_xor(S, 32);
    const float hwv = eh_ / S;

    float gmt = fmaxf(fmaxf(cm[0], cm[1]), fmaxf(cm[2], cm[3]));
    gmt = fmaxf(gmt, __shfl_xor(gmt, 1));
    gmt = fmaxf(gmt, __shfl_xor(gmt, 2));
    float et_[4];
    float St = 0.f;
    #pragma unroll
    for (int k = 0; k < 4; ++k) { et_[k] = expf(cm[k] - gmt); St += et_[k]; }
    St += __shfl_xor(St, 1);
    St += __shfl_xor(St, 2);

    if (jg == 0) hwS[wave][i] = hwv;
    if (lane < 4) {
        #pragma unroll
        for (int k = 0; k < 4; ++k) twS[wave][lane * 4 + k] = et_[k] / St;
    }
    __syncthreads();

    const size_t oh = (size_t)n * (2 * Hd);
    const size_t ot = (size_t)(N + n) * (2 * Hd);
    const unsigned short* fhp = f_head + (size_t)rh * Hd;
    const unsigned short* ftp = f_tail + (size_t)rt * Hd;

    // ---- head pooling: single pass over rows, 3 chunks/row, 2 rows/step ---
    {
        float a[12];
        #pragma unroll
        for (int j = 0; j < 12; ++j) a[j] = 0.f;
        int ii = 0;
        for (; ii + 2 <= hn; ii += 2) {
            u16x4 r0[3], r1[3];
            #pragma unroll
            for (int c = 0; c < 3; ++c) {
                r0[c] = *reinterpret_cast<const u16x4*>(fhp + (size_t)ii * Hd + c * 256 + lane * 4);
                r1[c] = *reinterpret_cast<const u16x4*>(fhp + (size_t)(ii + 1) * Hd + c * 256 + lane * 4);
            }
            const float w0 = hwS[wave][ii], w1 = hwS[wave][ii + 1];
            #pragma unroll
            for (int c = 0; c < 3; ++c)
                #pragma unroll
                for (int k = 0; k < 4; ++k) {
                    a[c * 4 + k] += w0 * bf2f(r0[c][k]);   // ascending ii:
                    a[c * 4 + k] += w1 * bf2f(r1[c][k]);   // bit-identical order
                }
        }
        if (ii < hn) {
            u16x4 r0[3];
            #pragma unroll
            for (int c = 0; c < 3; ++c)
                r0[c] = *reinterpret_cast<const u16x4*>(fhp + (size_t)ii * Hd + c * 256 + lane * 4);
            const float w0 = hwS[wave][ii];
            #pragma unroll
            for (int c = 0; c < 3; ++c)
                #pragma unroll
                for (int k = 0; k < 4; ++k)
                    a[c * 4 + k] += w0 * bf2f(r0[c][k]);
        }
        #pragma unroll
        for (int c = 0; c < 3; ++c) {
            float4 o = {a[c * 4], a[c * 4 + 1], a[c * 4 + 2], a[c * 4 + 3]};
            *reinterpret_cast<float4*>(out + oh + Hd + c * 256 + lane * 4) = o;
        }
    }

    // ---- tail pooling: same structure ----
    {
        float a[12];
        #pragma unroll
        for (int j = 0; j < 12; ++j) a[j] = 0.f;
        int ii = 0;
        for (; ii + 2 <= tn; ii += 2) {
            u16x4 r0[3], r1[3];
            #pragma unroll
            for (int c = 0; c < 3; ++c) {
                r0[c] = *reinterpret_cast<const u16x4*>(ftp + (size_t)ii * Hd + c * 256 + lane * 4);
                r1[c] = *reinterpret_cast<const u16x4*>(ftp + (size_t)(ii + 1) * Hd + c * 256 + lane * 4);
            }
            const float w0 = twS[wave][ii], w1 = twS[wave][ii + 1];
            #pragma unroll
            for (int c = 0; c < 3; ++c)
                #pragma unroll
                for (int k = 0; k < 4; ++k) {
                    a[c * 4 + k] += w0 * bf2f(r0[c][k]);
                    a[c * 4 + k] += w1 * bf2f(r1[c][k]);
                }
        }
        if (ii < tn) {
            u16x4 r0[3];
            #pragma unroll
            for (int c = 0; c < 3; ++c)
                r0[c] = *reinterpret_cast<const u16x4*>(ftp + (size_t)ii * Hd + c * 256 + lane * 4);
            const float w0 = twS[wave][ii];
            #pragma unroll
            for (int c = 0; c < 3; ++c)
                #pragma unroll
                for (int k = 0; k < 4; ++k)
                    a[c * 4 + k] += w0 * bf2f(r0[c][k]);
        }
        #pragma unroll
        for (int c = 0; c < 3; ++c) {
            float4 o = {a[c * 4], a[c * 4 + 1], a[c * 4 + 2], a[c * 4 + 3]};
            *reinterpret_cast<float4*>(out + ot + Hd + c * 256 + lane * 4) = o;
        }
    }

    // ---- entity embed copy: 2 x 192 float4, lane covers 3 each ----
    const float4* ehp = reinterpret_cast<const float4*>(entity_embed + (size_t)eh * Hd);
    const float4* etp = reinterpret_cast<const float4*>(entity_embed + (size_t)et * Hd);
    #pragma unroll
    for (int c = 0; c < 3; ++c) {
        const int g = c * 64 + lane;
        reinterpret_cast<float4*>(out + oh)[g] = ehp[g];
        reinterpret_cast<float4*>(out + ot)[g] = etp[g];
    }
}

// ---------------------------------------------------------------------------
extern "C" void kernel_launch(void* const* d_in, const int* in_sizes, int n_in,
                              void* d_out, int out_size, void* d_ws, size_t ws_size,
                              hipStream_t stream)
{
    const float* entity_embed  = (const float*)d_in[0];
    const float* mention_embed = (const float*)d_in[1];
    // d_in[2] sent_embed, d_in[3] entity_info: unused by reference
    const int*   mention_num   = (const int*)d_in[4];
    const int*   b_ind         = (const int*)d_in[5];
    const int*   h_ind         = (const int*)d_in[6];
    const int*   t_ind         = (const int*)d_in[7];
    const float* W_head        = (const float*)d_in[8];
    const float* W_tail        = (const float*)d_in[9];
    const float* w_c           = (const float*)d_in[10];
    const float* w_q           = (const float*)d_in[11];
    const float* w_cq          = (const float*)d_in[12];
    float* out = (float*)d_out;

    const int N = in_sizes[5];            // 4096

    // workspace layout (bf16 activations): total ~14.8 MiB
    unsigned short* Ab     = (unsigned short*)d_ws;          // [2688*768]
    unsigned short* Wb     = Ab + (size_t)GM * GK;           // [1536*768] (head||tail)
    unsigned short* f_head = Wb + (size_t)GN * GK;           // [2688*768]
    unsigned short* f_tail = f_head + (size_t)GM * Hd;       // [2688*768]
    float* ch  = (float*)(f_tail + (size_t)GM * Hd);         // [2688]
    float* qt  = ch + GM;                                    // [2688]
    float* cqt = qt + GM;                                    // [2688]

    // 0) convert inputs to bf16
    to_bf16<<<(GM + GN) * GK / (8 * 256), 256, 0, stream>>>(
        mention_embed, W_head, W_tail, Ab);

    // 1) GEMM + ReLU (BK=64, swizzled LDS)
    dim3 gg(GN / 128, GM / 64);           // (12, 42) = 504 blocks
    gemm_mfma<<<gg, 256, 0, stream>>>(Ab, Wb, f_head, f_tail);

    // 2) per-row dots
    row_dots<<<GM / 4, 256, 0, stream>>>(f_head, f_tail, w_c, w_q, w_cq, ch, qt, cqt);

    // 3) per-pair attention + output (wave per pair, 2-row MLP pooling)
    pair_attn<<<(N + 3) / 4, 256, 0, stream>>>(f_head, f_tail, ch, qt, cqt,
                                               entity_embed, mention_num,
                                               b_ind, h_ind, t_ind, out, N);
}